// Round 7
// baseline (323.060 us; speedup 1.0000x reference)
//
#include <hip/hip_runtime.h>
#include <hip/hip_bf16.h>

// Problem constants
#define BATCH 256
#define CDIM  512
#define NPOS  49        // 7*7 attention positions
#define MROWS 12544     // BATCH*NPOS
#define ASTRIDE 520     // fallback-kernel LDS stride

typedef __attribute__((ext_vector_type(8))) short bf16x8_t;  // MFMA A/B frag (4 VGPRs)
typedef __attribute__((ext_vector_type(4))) float f32x4_t;   // MFMA C/D frag

// ---------------------------------------------------------------------------
// ws layout (fast path):
//   Wab      bf16 [512][512]   @ 0         (524288)
//   pooled   bf16 [12544][512] @ 524288    (12845056)   packed rows b*49+n
//   ahb      f32  [256][512]   @ 13369344  (524288)     h@Wh^T + ba + bh
//   scores8  f32  [8][12544]   @ 13893632  (401408)     per-(nt,wn) partials
//   counters int  [256]        @ 14295040  (1024)       per-batch completion
// total 14296064 B
// ---------------------------------------------------------------------------
#define WS_NEED 14296064u

__device__ __forceinline__ void load_lds16(const void* g, void* l) {
    __builtin_amdgcn_global_load_lds(
        (const __attribute__((address_space(1))) void*)g,
        (__attribute__((address_space(3))) void*)l, 16, 0, 0);
}

// ===========================================================================
// K1 mega-kernel (grid 4385): independent block roles, SMALL ROLES FIRST so
// they overlap with the pool bulk instead of forming a serial tail.
//   bid == 0          : zero per-batch counters
//   1   <= bid <= 256 : Wa fp32 -> bf16 Wab (256 float4 per block)
//   257 <= bid <= 288 : MFMA tile GEMM  ahb = h @ Wh^T + ba + bh (64x64 tile)
//   bid >= 289        : 2x2 avg-pool att_v -> pooled
// ===========================================================================
__global__ __launch_bounds__(256, 6) void k1_pool_prep_ah(
    const float* __restrict__ att_v,   // [256,512,14,14]
    const float* __restrict__ h,       // [256,512]
    const float* __restrict__ Wa,      // [512,512]
    const float* __restrict__ Wh,      // [512,512]
    const float* __restrict__ ba, const float* __restrict__ bh,
    __hip_bfloat16* __restrict__ pooled,
    __hip_bfloat16* __restrict__ Wab,
    float* __restrict__ ahb,
    int* __restrict__ counters) {
    __shared__ float4 lds4[32 * 49];                 // 25088 B; aliased by ah role
    const int bid = blockIdx.x;
    const int t   = threadIdx.x;

    if (bid == 0) {
        counters[t] = 0;                             // 256 counters
    } else if (bid <= 256) {
        // ---------------- Wa -> bf16 ----------------
        const int idx = (bid - 1) * 256 + t;         // 0..65535 float4
        float4 v = ((const float4*)Wa)[idx];
        Wab[idx * 4 + 0] = __float2bfloat16(v.x);
        Wab[idx * 4 + 1] = __float2bfloat16(v.y);
        Wab[idx * 4 + 2] = __float2bfloat16(v.z);
        Wab[idx * 4 + 3] = __float2bfloat16(v.w);
    } else if (bid <= 288) {
        // ---------------- ah MFMA tile (fp32 inputs, inline convert) --------
        const int rel = bid - 257;                   // 0..31
        const int mt = rel & 3;                      // 4 x 64 over 256 b-rows
        const int nt = rel >> 2;                     // 8 x 64 over 512 d-cols
        const int m0 = mt * 64, n0 = nt * 64;
        __hip_bfloat16* aT = (__hip_bfloat16*)lds4;          // 64 x 32 (4 KB)
        __hip_bfloat16* bT = (__hip_bfloat16*)lds4 + 2048;   // 64 x 32 (4 KB)
        const int wave = t >> 6, lane = t & 63;
        const int wm = wave & 1, wn = wave >> 1;
        const int q = lane >> 4, r = lane & 15;
        const int row = t >> 2, cseg = (t & 3) * 8;  // staging: row, 8-col segment
        const float* hg = h  + (size_t)(m0 + row) * CDIM + cseg;
        const float* wg = Wh + (size_t)(n0 + row) * CDIM + cseg;

        f32x4_t acc[2][2];
        #pragma unroll
        for (int rt = 0; rt < 2; ++rt)
            #pragma unroll
            for (int ct = 0; ct < 2; ++ct) acc[rt][ct] = (f32x4_t){0.f, 0.f, 0.f, 0.f};

        for (int ks = 0; ks < 16; ++ks) {
            float4 a0 = *(const float4*)(hg + ks * 32);
            float4 a1 = *(const float4*)(hg + ks * 32 + 4);
            float4 b0 = *(const float4*)(wg + ks * 32);
            float4 b1 = *(const float4*)(wg + ks * 32 + 4);
            union { bf16x8_t v; __hip_bfloat16 e[8]; } ua, ub;
            ua.e[0] = __float2bfloat16(a0.x); ua.e[1] = __float2bfloat16(a0.y);
            ua.e[2] = __float2bfloat16(a0.z); ua.e[3] = __float2bfloat16(a0.w);
            ua.e[4] = __float2bfloat16(a1.x); ua.e[5] = __float2bfloat16(a1.y);
            ua.e[6] = __float2bfloat16(a1.z); ua.e[7] = __float2bfloat16(a1.w);
            ub.e[0] = __float2bfloat16(b0.x); ub.e[1] = __float2bfloat16(b0.y);
            ub.e[2] = __float2bfloat16(b0.z); ub.e[3] = __float2bfloat16(b0.w);
            ub.e[4] = __float2bfloat16(b1.x); ub.e[5] = __float2bfloat16(b1.y);
            ub.e[6] = __float2bfloat16(b1.z); ub.e[7] = __float2bfloat16(b1.w);
            __syncthreads();                          // reuse vs prev iter reads
            *(bf16x8_t*)&aT[row * 32 + cseg] = ua.v;
            *(bf16x8_t*)&bT[row * 32 + cseg] = ub.v;
            __syncthreads();
            bf16x8_t af[2], bf[2];
            #pragma unroll
            for (int rt = 0; rt < 2; ++rt)
                af[rt] = *(const bf16x8_t*)&aT[(wm * 32 + rt * 16 + r) * 32 + q * 8];
            #pragma unroll
            for (int ct = 0; ct < 2; ++ct)
                bf[ct] = *(const bf16x8_t*)&bT[(wn * 32 + ct * 16 + r) * 32 + q * 8];
            #pragma unroll
            for (int rt = 0; rt < 2; ++rt)
                #pragma unroll
                for (int ct = 0; ct < 2; ++ct)
                    acc[rt][ct] = __builtin_amdgcn_mfma_f32_16x16x32_bf16(
                        af[rt], bf[ct], acc[rt][ct], 0, 0, 0);
        }
        // C/D: col = r, row = q*4+reg
        #pragma unroll
        for (int ct = 0; ct < 2; ++ct) {
            const int col = n0 + wn * 32 + ct * 16 + r;
            const float bias = ba[col] + bh[col];
            #pragma unroll
            for (int rt = 0; rt < 2; ++rt)
                #pragma unroll
                for (int rg = 0; rg < 4; ++rg) {
                    const int orow = m0 + wm * 32 + rt * 16 + q * 4 + rg;
                    ahb[(size_t)orow * CDIM + col] = acc[rt][ct][rg] + bias;
                }
        }
    } else {
        // ---------------- pool (round-4 proven) ----------------
        const int rel = bid - 289;
        const int b  = rel >> 4;
        const int cg = rel & 15;
        const float4* src = (const float4*)(att_v + ((size_t)b * CDIM + cg * 32) * 196);
        #pragma unroll
        for (int k = 0; k < 7; ++k) {
            int idx = t + k * 256;
            if (idx < 1568) lds4[idx] = src[idx];
        }
        __syncthreads();
        const int i = t >> 5;                        // pooled row block 0..7 (7 active)
        const int c = t & 31;
        if (i < 7) {
            const float4* fp = &lds4[c * 49 + 7 * i];
            float4 f0 = fp[0], f1 = fp[1], f2 = fp[2], f3 = fp[3];
            float4 f4 = fp[4], f5 = fp[5], f6 = fp[6];
            float p[7];
            p[0] = f0.x + f0.y + f3.z + f3.w;
            p[1] = f0.z + f0.w + f4.x + f4.y;
            p[2] = f1.x + f1.y + f4.z + f4.w;
            p[3] = f1.z + f1.w + f5.x + f5.y;
            p[4] = f2.x + f2.y + f5.z + f5.w;
            p[5] = f2.z + f2.w + f6.x + f6.y;
            p[6] = f3.x + f3.y + f6.z + f6.w;
            __hip_bfloat16* outp =
                pooled + ((size_t)b * NPOS + i * 7) * CDIM + cg * 32 + c;
            #pragma unroll
            for (int j = 0; j < 7; ++j)
                outp[(size_t)j * CDIM] = __float2bfloat16(p[j] * 0.25f);
        }
    }
}

// ===========================================================================
// K2 gemm_score_fused: one block = (batch b, 128-col tile nt).  grid 1024.
// GEMM + tanh*Wd reduce as before (BK=64, 2 subtiles).  Then per-batch
// completion counter: the LAST of the 4 blocks for batch b sums the 8 score
// segments, does softmax over 49, and writes out[b][:] (weighted channel sum
// over pooled[b], L2-hot from this block's own A staging).
// Cross-block visibility: release fence -> device atomic -> acquire fence.
// ===========================================================================
__global__ __launch_bounds__(256, 4) void gemm_score_fused(
    const __hip_bfloat16* __restrict__ A,   // pooled [12544][512]
    const __hip_bfloat16* __restrict__ Bw,  // Wab [512][512]
    const float* __restrict__ ahb,          // [256][512]
    const float* __restrict__ Wd,           // [512]
    float* __restrict__ scores8,            // [8][12544]
    int* __restrict__ counters,             // [256]
    float* __restrict__ out) {              // [256][512]
    __shared__ __hip_bfloat16 aT[2 * 64 * 32];   // 8 KB  (2 subtiles)
    __shared__ __hip_bfloat16 bT[2 * 128 * 32];  // 16 KB (2 subtiles)
    __shared__ float s_w[NPOS];                  // softmax workspace
    __shared__ int   last_flag;
    const int b  = blockIdx.x >> 2;
    const int nt = blockIdx.x & 3;
    const int t = threadIdx.x;
    const int wave = t >> 6, lane = t & 63;
    const int wm = wave & 1, wn = wave >> 1;
    const int q = lane >> 4, r = lane & 15;
    const int m0 = b * NPOS;
    const int n0 = nt * 128;

    const __hip_bfloat16* Ag  = A  + (size_t)(m0 + (t >> 2)) * CDIM + (t & 3) * 8;
    const __hip_bfloat16* Bg0 = Bw + (size_t)(n0 + (t >> 2)) * CDIM + (t & 3) * 8;
    const __hip_bfloat16* Bg1 = Bw + (size_t)(n0 + 64 + (t >> 2)) * CDIM + (t & 3) * 8;
    char* aD = (char*)aT + t * 16;
    char* bD = (char*)bT + t * 16;

    f32x4_t acc[2][4];                       // [row-tile][col-tile]
    #pragma unroll
    for (int rt = 0; rt < 2; ++rt)
        #pragma unroll
        for (int ct = 0; ct < 4; ++ct) acc[rt][ct] = (f32x4_t){0.f, 0.f, 0.f, 0.f};

    for (int ks = 0; ks < 8; ++ks) {
        const int k0 = ks * 64;
        load_lds16(Ag + k0, aD);
        load_lds16(Ag + k0 + 32, aD + 4096);
        load_lds16(Bg0 + k0, bD);
        load_lds16(Bg1 + k0, bD + 4096);
        load_lds16(Bg0 + k0 + 32, bD + 8192);
        load_lds16(Bg1 + k0 + 32, bD + 12288);
        __syncthreads();
        #pragma unroll
        for (int s = 0; s < 2; ++s) {
            const __hip_bfloat16* aS = aT + s * 2048;
            const __hip_bfloat16* bS = bT + s * 4096;
            bf16x8_t af[2], bf[4];
            #pragma unroll
            for (int rt = 0; rt < 2; ++rt)
                af[rt] = *(const bf16x8_t*)&aS[(wm * 32 + rt * 16 + r) * 32 + q * 8];
            #pragma unroll
            for (int ct = 0; ct < 4; ++ct)
                bf[ct] = *(const bf16x8_t*)&bS[(wn * 64 + ct * 16 + r) * 32 + q * 8];
            #pragma unroll
            for (int rt = 0; rt < 2; ++rt)
                #pragma unroll
                for (int ct = 0; ct < 4; ++ct)
                    acc[rt][ct] = __builtin_amdgcn_mfma_f32_16x16x32_bf16(
                        af[rt], bf[ct], acc[rt][ct], 0, 0, 0);
        }
        __syncthreads();
    }

    // --- tanh*Wd column reduction.  Rows: wm*32+rt*16+q*4+rg; cols: n0+wn*64+ct*16+r.
    float rsum[2][4];
    #pragma unroll
    for (int rt = 0; rt < 2; ++rt)
        #pragma unroll
        for (int rg = 0; rg < 4; ++rg) rsum[rt][rg] = 0.f;

    const float* ahp = ahb + (size_t)b * CDIM;
    #pragma unroll
    for (int ct = 0; ct < 4; ++ct) {
        const int col = n0 + wn * 64 + ct * 16 + r;
        const float ah = ahp[col];
        const float wd = Wd[col];
        #pragma unroll
        for (int rt = 0; rt < 2; ++rt)
            #pragma unroll
            for (int rg = 0; rg < 4; ++rg) {
                float x = acc[rt][ct][rg] + ah;
                float e = __expf(2.f * x);               // tanh = 1 - 2/(e^{2x}+1)
                rsum[rt][rg] += (1.f - 2.f / (e + 1.f)) * wd;
            }
    }
    #pragma unroll
    for (int m = 1; m < 16; m <<= 1)
        #pragma unroll
        for (int rt = 0; rt < 2; ++rt)
            #pragma unroll
            for (int rg = 0; rg < 4; ++rg)
                rsum[rt][rg] += __shfl_xor(rsum[rt][rg], m, 64);
    if (r == 0) {
        float* seg = scores8 + (size_t)(nt * 2 + wn) * MROWS + m0;
        #pragma unroll
        for (int rt = 0; rt < 2; ++rt)
            #pragma unroll
            for (int rg = 0; rg < 4; ++rg) {
                const int row = wm * 32 + rt * 16 + q * 4 + rg;
                if (row < NPOS) seg[row] = rsum[rt][rg];
            }
    }

    // --- per-batch completion: last of 4 blocks does softmax + weighted sum.
    __threadfence();                 // release: make score stores visible
    __syncthreads();                 // all waves' stores + fences done
    if (t == 0) last_flag = (atomicAdd(&counters[b], 1) == 3);
    __syncthreads();
    if (!last_flag) return;
    __threadfence();                 // acquire: invalidate stale cached lines

    if (t < NPOS) {
        float s = 0.f;
        #pragma unroll
        for (int seg = 0; seg < 8; ++seg)
            s += scores8[(size_t)seg * MROWS + m0 + t];
        s_w[t] = s;
    }
    __syncthreads();
    if (t < NPOS) {
        float vmax = -3.0e38f;
        #pragma unroll
        for (int n = 0; n < NPOS; ++n) vmax = fmaxf(vmax, s_w[n]);
        float S = 0.f;
        #pragma unroll
        for (int n = 0; n < NPOS; ++n) S += __expf(s_w[n] - vmax);
        float e = __expf(s_w[t] - vmax);
        __syncthreads();             // reads of s_w done before overwrite
        s_w[t] = e / S;              // normalized weight
    } else {
        __syncthreads();
    }
    __syncthreads();

    const __hip_bfloat16* Ap = A + (size_t)m0 * CDIM;
    float a0 = 0.f, a1 = 0.f;
    #pragma unroll
    for (int n = 0; n < NPOS; ++n) {
        const float w = s_w[n];
        a0 += w * __bfloat162float(Ap[(size_t)n * CDIM + t]);
        a1 += w * __bfloat162float(Ap[(size_t)n * CDIM + t + 256]);
    }
    out[b * CDIM + t]       = a0;
    out[b * CDIM + t + 256] = a1;
}

// ===========================================================================
// Fallback path (round-1, 1 MB ws) — used only if ws too small.
// ===========================================================================
__global__ void prep_convert(const float* __restrict__ Wa,
                             const float* __restrict__ Wh,
                             __hip_bfloat16* __restrict__ Wab,
                             __hip_bfloat16* __restrict__ Whb) {
    int gid = blockIdx.x * blockDim.x + threadIdx.x;
    const int quarter = (CDIM * CDIM) / 4;
    const float4* src; __hip_bfloat16* dst; int idx;
    if (gid < quarter) { src = (const float4*)Wa; dst = Wab; idx = gid; }
    else               { src = (const float4*)Wh; dst = Whb; idx = gid - quarter; }
    float4 v = src[idx];
    dst[idx * 4 + 0] = __float2bfloat16(v.x);
    dst[idx * 4 + 1] = __float2bfloat16(v.y);
    dst[idx * 4 + 2] = __float2bfloat16(v.z);
    dst[idx * 4 + 3] = __float2bfloat16(v.w);
}

__global__ __launch_bounds__(512, 2) void att_spp_main(
    const float* __restrict__ att_v, const float* __restrict__ h,
    const float* __restrict__ ba, const float* __restrict__ bh,
    const float* __restrict__ Wd,
    const __hip_bfloat16* __restrict__ Wab, const __hip_bfloat16* __restrict__ Whb,
    float* __restrict__ out) {
    __shared__ __hip_bfloat16 a_lds[64 * ASTRIDE];
    __shared__ __hip_bfloat16 h_lds[CDIM];
    __shared__ float babh_lds[CDIM];
    __shared__ float wd_lds[CDIM];
    __shared__ float scores_lds[64];
    __shared__ float weights_lds[NPOS];
    const int b = blockIdx.x, t = threadIdx.x;
    h_lds[t]    = __float2bfloat16(h[b * CDIM + t]);
    babh_lds[t] = ba[t] + bh[t];
    wd_lds[t]   = Wd[t];
    if (t < 64) scores_lds[t] = 0.f;
    for (int idx = t; idx < (64 - NPOS) * ASTRIDE; idx += 512)
        a_lds[NPOS * ASTRIDE + idx] = __float2bfloat16(0.f);
    {
        const int jj = t & 7, g = t >> 3;
        const float2* att2 = (const float2*)(att_v + (size_t)b * CDIM * 196);
        if (jj < 7) {
            for (int ci = 0; ci < 8; ++ci) {
                const int c = g + (ci << 6), cbase = c * 98;
                #pragma unroll
                for (int i = 0; i < 7; ++i) {
                    float2 v0 = att2[cbase + i * 14 + jj];
                    float2 v1 = att2[cbase + i * 14 + 7 + jj];
                    a_lds[(i * 7 + jj) * ASTRIDE + c] =
                        __float2bfloat16((v0.x + v0.y + v1.x + v1.y) * 0.25f);
                }
            }
        }
    }
    __syncthreads();
    const int wave = t >> 6, lane = t & 63, q = lane >> 4, r = lane & 15;
    f32x4_t acc[4][4];
    #pragma unroll
    for (int rt = 0; rt < 4; ++rt)
        #pragma unroll
        for (int ct = 0; ct < 4; ++ct) acc[rt][ct] = (f32x4_t){0.f,0.f,0.f,0.f};
    const int dBase = wave * 64 + r;
    for (int ks = 0; ks < 16; ++ks) {
        const int k0 = ks * 32 + q * 8;
        bf16x8_t af[4], bf[4];
        #pragma unroll
        for (int rt = 0; rt < 4; ++rt)
            af[rt] = *(const bf16x8_t*)&a_lds[(rt * 16 + r) * ASTRIDE + k0];
        #pragma unroll
        for (int ct = 0; ct < 4; ++ct)
            bf[ct] = *(const bf16x8_t*)&Wab[(size_t)(dBase + ct * 16) * CDIM + k0];
        #pragma unroll
        for (int rt = 0; rt < 4; ++rt)
            #pragma unroll
            for (int ct = 0; ct < 4; ++ct)
                acc[rt][ct] = __builtin_amdgcn_mfma_f32_16x16x32_bf16(
                    af[rt], bf[ct], acc[rt][ct], 0, 0, 0);
    }
    for (int ks = 0; ks < 16; ++ks) {
        const int k0 = ks * 32 + q * 8;
        bf16x8_t af = *(const bf16x8_t*)&h_lds[k0];
        bf16x8_t bf[4];
        #pragma unroll
        for (int ct = 0; ct < 4; ++ct)
            bf[ct] = *(const bf16x8_t*)&Whb[(size_t)(dBase + ct * 16) * CDIM + k0];
        #pragma unroll
        for (int rt = 0; rt < 4; ++rt)
            #pragma unroll
            for (int ct = 0; ct < 4; ++ct)
                acc[rt][ct] = __builtin_amdgcn_mfma_f32_16x16x32_bf16(
                    af, bf[ct], acc[rt][ct], 0, 0, 0);
    }
    float part[4][4];
    #pragma unroll
    for (int rt = 0; rt < 4; ++rt)
        #pragma unroll
        for (int rg = 0; rg < 4; ++rg) part[rt][rg] = 0.f;
    #pragma unroll
    for (int ct = 0; ct < 4; ++ct) {
        const int d = dBase + ct * 16;
        const float bias = babh_lds[d], wd = wd_lds[d];
        #pragma unroll
        for (int rt = 0; rt < 4; ++rt)
            #pragma unroll
            for (int rg = 0; rg < 4; ++rg) {
                float x = acc[rt][ct][rg] + bias;
                float e = __expf(2.f * x);
                part[rt][rg] += (1.f - 2.f / (e + 1.f)) * wd;
            }
    }
    #pragma unroll
    for (int m = 1; m < 16; m <<= 1)
        #pragma unroll
        for (int rt = 0; rt < 4; ++rt)
            #pragma unroll
            for (int rg = 0; rg < 4; ++rg)
                part[rt][rg] += __shfl_xor(part[rt][rg], m, 64);
    if (r == 0) {
        #pragma unroll
        for (int rt = 0; rt < 4; ++rt)
            #pragma unroll
            for (int rg = 0; rg < 4; ++rg)
                atomicAdd(&scores_lds[rt * 16 + q * 4 + rg], part[rt][rg]);
    }
    __syncthreads();
    if (wave == 0) {
        float v = (lane < NPOS) ? scores_lds[lane] : -3.0e38f;
        float vmax = v;
        #pragma unroll
        for (int m = 1; m < 64; m <<= 1) vmax = fmaxf(vmax, __shfl_xor(vmax, m, 64));
        float e = (lane < NPOS) ? __expf(v - vmax) : 0.f;
        float s = e;
        #pragma unroll
        for (int m = 1; m < 64; m <<= 1) s += __shfl_xor(s, m, 64);
        if (lane < NPOS) weights_lds[lane] = e / s;
    }
    __syncthreads();
    float sum = 0.f;
    #pragma unroll
    for (int n = 0; n < NPOS; ++n)
        sum += __bfloat162float(a_lds[n * ASTRIDE + t]) * weights_lds[n];
    out[b * CDIM + t] = sum;
}

// ===========================================================================
extern "C" void kernel_launch(void* const* d_in, const int* in_sizes, int n_in,
                              void* d_out, int out_size, void* d_ws, size_t ws_size,
                              hipStream_t stream) {
    const float* att_v = (const float*)d_in[0];
    const float* h     = (const float*)d_in[1];
    const float* Wa    = (const float*)d_in[2];
    const float* ba    = (const float*)d_in[3];
    const float* Wh    = (const float*)d_in[4];
    const float* bh    = (const float*)d_in[5];
    const float* Wd    = (const float*)d_in[6];
    // d_in[7] = bd: dropped (softmax shift-invariant)

    if (ws_size >= WS_NEED) {
        char* ws = (char*)d_ws;
        __hip_bfloat16* Wab     = (__hip_bfloat16*)(ws);
        __hip_bfloat16* pooled  = (__hip_bfloat16*)(ws + 524288);
        float*          ahb     = (float*)(ws + 13369344);
        float*          scores8 = (float*)(ws + 13893632);
        int*            counters= (int*)(ws + 14295040);

        k1_pool_prep_ah<<<4385, 256, 0, stream>>>(att_v, h, Wa, Wh, ba, bh,
                                                  pooled, Wab, ahb, counters);
        gemm_score_fused<<<1024, 256, 0, stream>>>(pooled, Wab, ahb, Wd,
                                                   scores8, counters,
                                                   (float*)d_out);
    } else {
        __hip_bfloat16* Wab = (__hip_bfloat16*)d_ws;
        __hip_bfloat16* Whb = Wab + (size_t)CDIM * CDIM;
        prep_convert<<<512, 256, 0, stream>>>(Wa, Wh, Wab, Whb);
        att_spp_main<<<BATCH, 512, 0, stream>>>(att_v, h, ba, bh, Wd, Wab, Whb,
                                                (float*)d_out);
    }
}

// Round 8
// 187.447 us; speedup vs baseline: 1.7235x; 1.7235x over previous
//
#include <hip/hip_runtime.h>
#include <hip/hip_bf16.h>

// Problem constants
#define BATCH 256
#define CDIM  512
#define NPOS  49        // 7*7 attention positions
#define MROWS 12544     // BATCH*NPOS
#define ASTRIDE 520     // fallback-kernel LDS stride

typedef __attribute__((ext_vector_type(8))) short bf16x8_t;  // MFMA A/B frag (4 VGPRs)
typedef __attribute__((ext_vector_type(4))) float f32x4_t;   // MFMA C/D frag

// ---------------------------------------------------------------------------
// ws layout (fast path):
//   Wab      bf16 [512][512]   @ 0         (524288)
//   pooled   bf16 [12544][512] @ 524288    (12845056)   packed rows b*49+n
//   ahb      f32  [256][512]   @ 13369344  (524288)     h@Wh^T + ba + bh
//   scores   f32  [256][64]    @ 13893632  (65536)      atomic accumulators
//   counters int  [256]        @ 13959168  (1024)       per-batch completion
// total 13960192 B
// ---------------------------------------------------------------------------
#define WS_NEED 13960192u

__device__ __forceinline__ void load_lds16(const void* g, void* l) {
    __builtin_amdgcn_global_load_lds(
        (const __attribute__((address_space(1))) void*)g,
        (__attribute__((address_space(3))) void*)l, 16, 0, 0);
}

// ===========================================================================
// K1 mega-kernel (grid 4401): independent block roles, small roles first so
// they overlap with the pool bulk instead of forming a serial tail.
//   bid 0..15    : zero scores (4096 float4)
//   bid == 16    : zero counters (64 float4)
//   bid 17..272  : Wa fp32 -> bf16 Wab (256 float4 per block)
//   bid 273..304 : MFMA tile GEMM  ahb = h @ Wh^T + ba + bh (64x64 tile)
//   bid >= 305   : 2x2 avg-pool att_v -> pooled
// ===========================================================================
__global__ __launch_bounds__(256, 6) void k1_pool_prep_ah(
    const float* __restrict__ att_v,   // [256,512,14,14]
    const float* __restrict__ h,       // [256,512]
    const float* __restrict__ Wa,      // [512,512]
    const float* __restrict__ Wh,      // [512,512]
    const float* __restrict__ ba, const float* __restrict__ bh,
    __hip_bfloat16* __restrict__ pooled,
    __hip_bfloat16* __restrict__ Wab,
    float* __restrict__ ahb,
    float* __restrict__ scores,
    int* __restrict__ counters) {
    __shared__ float4 lds4[32 * 49];                 // 25088 B; aliased by ah role
    const int bid = blockIdx.x;
    const int t   = threadIdx.x;

    if (bid < 16) {
        ((float4*)scores)[bid * 256 + t] = (float4){0.f, 0.f, 0.f, 0.f};
    } else if (bid == 16) {
        if (t < 64) ((float4*)counters)[t] = (float4){0.f, 0.f, 0.f, 0.f};
    } else if (bid < 273) {
        // ---------------- Wa -> bf16 ----------------
        const int idx = (bid - 17) * 256 + t;        // 0..65535 float4
        float4 v = ((const float4*)Wa)[idx];
        Wab[idx * 4 + 0] = __float2bfloat16(v.x);
        Wab[idx * 4 + 1] = __float2bfloat16(v.y);
        Wab[idx * 4 + 2] = __float2bfloat16(v.z);
        Wab[idx * 4 + 3] = __float2bfloat16(v.w);
    } else if (bid < 305) {
        // ---------------- ah MFMA tile (fp32 inputs, inline convert) --------
        const int rel = bid - 273;                   // 0..31
        const int mt = rel & 3;                      // 4 x 64 over 256 b-rows
        const int nt = rel >> 2;                     // 8 x 64 over 512 d-cols
        const int m0 = mt * 64, n0 = nt * 64;
        __hip_bfloat16* aT = (__hip_bfloat16*)lds4;          // 64 x 32 (4 KB)
        __hip_bfloat16* bT = (__hip_bfloat16*)lds4 + 2048;   // 64 x 32 (4 KB)
        const int wave = t >> 6, lane = t & 63;
        const int wm = wave & 1, wn = wave >> 1;
        const int q = lane >> 4, r = lane & 15;
        const int row = t >> 2, cseg = (t & 3) * 8;  // staging: row, 8-col segment
        const float* hg = h  + (size_t)(m0 + row) * CDIM + cseg;
        const float* wg = Wh + (size_t)(n0 + row) * CDIM + cseg;

        f32x4_t acc[2][2];
        #pragma unroll
        for (int rt = 0; rt < 2; ++rt)
            #pragma unroll
            for (int ct = 0; ct < 2; ++ct) acc[rt][ct] = (f32x4_t){0.f, 0.f, 0.f, 0.f};

        for (int ks = 0; ks < 16; ++ks) {
            float4 a0 = *(const float4*)(hg + ks * 32);
            float4 a1 = *(const float4*)(hg + ks * 32 + 4);
            float4 b0 = *(const float4*)(wg + ks * 32);
            float4 b1 = *(const float4*)(wg + ks * 32 + 4);
            union { bf16x8_t v; __hip_bfloat16 e[8]; } ua, ub;
            ua.e[0] = __float2bfloat16(a0.x); ua.e[1] = __float2bfloat16(a0.y);
            ua.e[2] = __float2bfloat16(a0.z); ua.e[3] = __float2bfloat16(a0.w);
            ua.e[4] = __float2bfloat16(a1.x); ua.e[5] = __float2bfloat16(a1.y);
            ua.e[6] = __float2bfloat16(a1.z); ua.e[7] = __float2bfloat16(a1.w);
            ub.e[0] = __float2bfloat16(b0.x); ub.e[1] = __float2bfloat16(b0.y);
            ub.e[2] = __float2bfloat16(b0.z); ub.e[3] = __float2bfloat16(b0.w);
            ub.e[4] = __float2bfloat16(b1.x); ub.e[5] = __float2bfloat16(b1.y);
            ub.e[6] = __float2bfloat16(b1.z); ub.e[7] = __float2bfloat16(b1.w);
            __syncthreads();
            *(bf16x8_t*)&aT[row * 32 + cseg] = ua.v;
            *(bf16x8_t*)&bT[row * 32 + cseg] = ub.v;
            __syncthreads();
            bf16x8_t af[2], bf[2];
            #pragma unroll
            for (int rt = 0; rt < 2; ++rt)
                af[rt] = *(const bf16x8_t*)&aT[(wm * 32 + rt * 16 + r) * 32 + q * 8];
            #pragma unroll
            for (int ct = 0; ct < 2; ++ct)
                bf[ct] = *(const bf16x8_t*)&bT[(wn * 32 + ct * 16 + r) * 32 + q * 8];
            #pragma unroll
            for (int rt = 0; rt < 2; ++rt)
                #pragma unroll
                for (int ct = 0; ct < 2; ++ct)
                    acc[rt][ct] = __builtin_amdgcn_mfma_f32_16x16x32_bf16(
                        af[rt], bf[ct], acc[rt][ct], 0, 0, 0);
        }
        // C/D: col = r, row = q*4+reg
        #pragma unroll
        for (int ct = 0; ct < 2; ++ct) {
            const int col = n0 + wn * 32 + ct * 16 + r;
            const float bias = ba[col] + bh[col];
            #pragma unroll
            for (int rt = 0; rt < 2; ++rt)
                #pragma unroll
                for (int rg = 0; rg < 4; ++rg) {
                    const int orow = m0 + wm * 32 + rt * 16 + q * 4 + rg;
                    ahb[(size_t)orow * CDIM + col] = acc[rt][ct][rg] + bias;
                }
        }
    } else {
        // ---------------- pool (round-4 proven) ----------------
        const int rel = bid - 305;
        const int b  = rel >> 4;
        const int cg = rel & 15;
        const float4* src = (const float4*)(att_v + ((size_t)b * CDIM + cg * 32) * 196);
        #pragma unroll
        for (int k = 0; k < 7; ++k) {
            int idx = t + k * 256;
            if (idx < 1568) lds4[idx] = src[idx];
        }
        __syncthreads();
        const int i = t >> 5;                        // pooled row block 0..7 (7 active)
        const int c = t & 31;
        if (i < 7) {
            const float4* fp = &lds4[c * 49 + 7 * i];
            float4 f0 = fp[0], f1 = fp[1], f2 = fp[2], f3 = fp[3];
            float4 f4 = fp[4], f5 = fp[5], f6 = fp[6];
            float p[7];
            p[0] = f0.x + f0.y + f3.z + f3.w;
            p[1] = f0.z + f0.w + f4.x + f4.y;
            p[2] = f1.x + f1.y + f4.z + f4.w;
            p[3] = f1.z + f1.w + f5.x + f5.y;
            p[4] = f2.x + f2.y + f5.z + f5.w;
            p[5] = f2.z + f2.w + f6.x + f6.y;
            p[6] = f3.x + f3.y + f6.z + f6.w;
            __hip_bfloat16* outp =
                pooled + ((size_t)b * NPOS + i * 7) * CDIM + cg * 32 + c;
            #pragma unroll
            for (int j = 0; j < 7; ++j)
                outp[(size_t)j * CDIM] = __float2bfloat16(p[j] * 0.25f);
        }
    }
}

// ===========================================================================
// K2 gemm_score_fused2: one block = (batch b, 128-col tile nt).  grid 1024.
// GEMM core = round-6 proven (BK=64, 2 subtiles) + XOR seg-swizzle on the
// STAGING GLOBAL ADDRESS (LDS side stays linear -> legal with global_load_lds
// wave-uniform-base semantics); frag reads apply the same swizzle -> 2
// lanes/bank (free).  Epilogue: tanh*Wd reduce -> global atomicAdd scores
// (device-scope, coherent at L2 point, NO cache-maintenance fences) ->
// s_waitcnt vmcnt(0) (ordering only) -> counter atomic; last of 4 blocks
// re-reads scores via atomicAdd(p,0), softmax over 49, weighted sum -> out.
// ===========================================================================
__global__ __launch_bounds__(256, 4) void gemm_score_fused2(
    const __hip_bfloat16* __restrict__ A,   // pooled [12544][512]
    const __hip_bfloat16* __restrict__ Bw,  // Wab [512][512]
    const float* __restrict__ ahb,          // [256][512]
    const float* __restrict__ Wd,           // [512]
    float* __restrict__ scores,             // [256][64]
    int* __restrict__ counters,             // [256]
    float* __restrict__ out) {              // [256][512]
    __shared__ __hip_bfloat16 aT[2 * 64 * 32];   // 8 KB  (2 subtiles)
    __shared__ __hip_bfloat16 bT[2 * 128 * 32];  // 16 KB (2 subtiles)
    __shared__ float s_raw[NPOS];
    __shared__ float w_w[NPOS];
    __shared__ int   last_flag;
    const int b  = blockIdx.x >> 2;
    const int nt = blockIdx.x & 3;
    const int t = threadIdx.x;
    const int wave = t >> 6, lane = t & 63;
    const int wm = wave & 1, wn = wave >> 1;
    const int q = lane >> 4, r = lane & 15;
    const int m0 = b * NPOS;
    const int n0 = nt * 128;

    // Staging: thread t covers row t>>2; swizzled 16B segment (t&3)^((t>>3)&3).
    const int srow = t >> 2;
    const int sseg = (t & 3) ^ ((t >> 3) & 3);
    const __hip_bfloat16* Ag  = A  + (size_t)(m0 + srow) * CDIM + sseg * 8;
    const __hip_bfloat16* Bg0 = Bw + (size_t)(n0 + srow) * CDIM + sseg * 8;
    const __hip_bfloat16* Bg1 = Bw + (size_t)(n0 + 64 + srow) * CDIM + sseg * 8;
    char* aD = (char*)aT + t * 16;
    char* bD = (char*)bT + t * 16;

    f32x4_t acc[2][4];                       // [row-tile][col-tile]
    #pragma unroll
    for (int rt = 0; rt < 2; ++rt)
        #pragma unroll
        for (int ct = 0; ct < 4; ++ct) acc[rt][ct] = (f32x4_t){0.f, 0.f, 0.f, 0.f};

    for (int ks = 0; ks < 8; ++ks) {
        const int k0 = ks * 64;
        load_lds16(Ag + k0, aD);
        load_lds16(Ag + k0 + 32, aD + 4096);
        load_lds16(Bg0 + k0, bD);
        load_lds16(Bg1 + k0, bD + 4096);
        load_lds16(Bg0 + k0 + 32, bD + 8192);
        load_lds16(Bg1 + k0 + 32, bD + 12288);
        __syncthreads();
        #pragma unroll
        for (int s = 0; s < 2; ++s) {
            const __hip_bfloat16* aS = aT + s * 2048;
            const __hip_bfloat16* bS = bT + s * 4096;
            bf16x8_t af[2], bf[4];
            #pragma unroll
            for (int rt = 0; rt < 2; ++rt) {
                const int ar = wm * 32 + rt * 16 + r;
                af[rt] = *(const bf16x8_t*)&aS[ar * 32 + (q ^ ((ar >> 1) & 3)) * 8];
            }
            #pragma unroll
            for (int ct = 0; ct < 4; ++ct) {
                const int br = wn * 64 + ct * 16 + r;
                bf[ct] = *(const bf16x8_t*)&bS[br * 32 + (q ^ ((br >> 1) & 3)) * 8];
            }
            #pragma unroll
            for (int rt = 0; rt < 2; ++rt)
                #pragma unroll
                for (int ct = 0; ct < 4; ++ct)
                    acc[rt][ct] = __builtin_amdgcn_mfma_f32_16x16x32_bf16(
                        af[rt], bf[ct], acc[rt][ct], 0, 0, 0);
        }
        __syncthreads();
    }

    // --- tanh*Wd column reduction.  Rows: wm*32+rt*16+q*4+rg; cols: n0+wn*64+ct*16+r.
    float rsum[2][4];
    #pragma unroll
    for (int rt = 0; rt < 2; ++rt)
        #pragma unroll
        for (int rg = 0; rg < 4; ++rg) rsum[rt][rg] = 0.f;

    const float* ahp = ahb + (size_t)b * CDIM;
    #pragma unroll
    for (int ct = 0; ct < 4; ++ct) {
        const int col = n0 + wn * 64 + ct * 16 + r;
        const float ah = ahp[col];
        const float wd = Wd[col];
        #pragma unroll
        for (int rt = 0; rt < 2; ++rt)
            #pragma unroll
            for (int rg = 0; rg < 4; ++rg) {
                float x = acc[rt][ct][rg] + ah;
                float e = __expf(2.f * x);               // tanh = 1 - 2/(e^{2x}+1)
                rsum[rt][rg] += (1.f - 2.f / (e + 1.f)) * wd;
            }
    }
    #pragma unroll
    for (int m = 1; m < 16; m <<= 1)
        #pragma unroll
        for (int rt = 0; rt < 2; ++rt)
            #pragma unroll
            for (int rg = 0; rg < 4; ++rg)
                rsum[rt][rg] += __shfl_xor(rsum[rt][rg], m, 64);
    if (r == 0) {
        float* sb = scores + b * 64;
        #pragma unroll
        for (int rt = 0; rt < 2; ++rt)
            #pragma unroll
            for (int rg = 0; rg < 4; ++rg) {
                const int row = wm * 32 + rt * 16 + q * 4 + rg;
                if (row < NPOS) atomicAdd(&sb[row], rsum[rt][rg]);
            }
    }

    // --- per-batch completion via atomics only (NO __threadfence: its L2
    // writeback/invalidate serialized catastrophically in round 7).
    asm volatile("s_waitcnt vmcnt(0)" ::: "memory");   // order score-atomics
    __syncthreads();                                   // before counter atomic
    if (t == 0) last_flag = (atomicAdd(&counters[b], 1) == 3);
    __syncthreads();
    if (!last_flag) return;

    // Winner: coherent re-read of scores via atomic RMW (bypasses L1).
    if (t < NPOS) s_raw[t] = atomicAdd(&scores[b * 64 + t], 0.0f);
    __syncthreads();
    if (t < NPOS) {
        float vmax = -3.0e38f;
        #pragma unroll
        for (int n = 0; n < NPOS; ++n) vmax = fmaxf(vmax, s_raw[n]);
        float S = 0.f;
        #pragma unroll
        for (int n = 0; n < NPOS; ++n) S += __expf(s_raw[n] - vmax);
        w_w[t] = __expf(s_raw[t] - vmax) / S;
    }
    __syncthreads();

    const __hip_bfloat16* Ap = A + (size_t)m0 * CDIM;  // clean data from K1
    float a0 = 0.f, a1 = 0.f;
    #pragma unroll
    for (int n = 0; n < NPOS; ++n) {
        const float w = w_w[n];
        a0 += w * __bfloat162float(Ap[(size_t)n * CDIM + t]);
        a1 += w * __bfloat162float(Ap[(size_t)n * CDIM + t + 256]);
    }
    out[b * CDIM + t]       = a0;
    out[b * CDIM + t + 256] = a1;
}

// ===========================================================================
// Fallback path (round-1, 1 MB ws) — used only if ws too small.
// ===========================================================================
__global__ void prep_convert(const float* __restrict__ Wa,
                             const float* __restrict__ Wh,
                             __hip_bfloat16* __restrict__ Wab,
                             __hip_bfloat16* __restrict__ Whb) {
    int gid = blockIdx.x * blockDim.x + threadIdx.x;
    const int quarter = (CDIM * CDIM) / 4;
    const float4* src; __hip_bfloat16* dst; int idx;
    if (gid < quarter) { src = (const float4*)Wa; dst = Wab; idx = gid; }
    else               { src = (const float4*)Wh; dst = Whb; idx = gid - quarter; }
    float4 v = src[idx];
    dst[idx * 4 + 0] = __float2bfloat16(v.x);
    dst[idx * 4 + 1] = __float2bfloat16(v.y);
    dst[idx * 4 + 2] = __float2bfloat16(v.z);
    dst[idx * 4 + 3] = __float2bfloat16(v.w);
}

__global__ __launch_bounds__(512, 2) void att_spp_main(
    const float* __restrict__ att_v, const float* __restrict__ h,
    const float* __restrict__ ba, const float* __restrict__ bh,
    const float* __restrict__ Wd,
    const __hip_bfloat16* __restrict__ Wab, const __hip_bfloat16* __restrict__ Whb,
    float* __restrict__ out) {
    __shared__ __hip_bfloat16 a_lds[64 * ASTRIDE];
    __shared__ __hip_bfloat16 h_lds[CDIM];
    __shared__ float babh_lds[CDIM];
    __shared__ float wd_lds[CDIM];
    __shared__ float scores_lds[64];
    __shared__ float weights_lds[NPOS];
    const int b = blockIdx.x, t = threadIdx.x;
    h_lds[t]    = __float2bfloat16(h[b * CDIM + t]);
    babh_lds[t] = ba[t] + bh[t];
    wd_lds[t]   = Wd[t];
    if (t < 64) scores_lds[t] = 0.f;
    for (int idx = t; idx < (64 - NPOS) * ASTRIDE; idx += 512)
        a_lds[NPOS * ASTRIDE + idx] = __float2bfloat16(0.f);
    {
        const int jj = t & 7, g = t >> 3;
        const float2* att2 = (const float2*)(att_v + (size_t)b * CDIM * 196);
        if (jj < 7) {
            for (int ci = 0; ci < 8; ++ci) {
                const int c = g + (ci << 6), cbase = c * 98;
                #pragma unroll
                for (int i = 0; i < 7; ++i) {
                    float2 v0 = att2[cbase + i * 14 + jj];
                    float2 v1 = att2[cbase + i * 14 + 7 + jj];
                    a_lds[(i * 7 + jj) * ASTRIDE + c] =
                        __float2bfloat16((v0.x + v0.y + v1.x + v1.y) * 0.25f);
                }
            }
        }
    }
    __syncthreads();
    const int wave = t >> 6, lane = t & 63, q = lane >> 4, r = lane & 15;
    f32x4_t acc[4][4];
    #pragma unroll
    for (int rt = 0; rt < 4; ++rt)
        #pragma unroll
        for (int ct = 0; ct < 4; ++ct) acc[rt][ct] = (f32x4_t){0.f,0.f,0.f,0.f};
    const int dBase = wave * 64 + r;
    for (int ks = 0; ks < 16; ++ks) {
        const int k0 = ks * 32 + q * 8;
        bf16x8_t af[4], bf[4];
        #pragma unroll
        for (int rt = 0; rt < 4; ++rt)
            af[rt] = *(const bf16x8_t*)&a_lds[(rt * 16 + r) * ASTRIDE + k0];
        #pragma unroll
        for (int ct = 0; ct < 4; ++ct)
            bf[ct] = *(const bf16x8_t*)&Wab[(size_t)(dBase + ct * 16) * CDIM + k0];
        #pragma unroll
        for (int rt = 0; rt < 4; ++rt)
            #pragma unroll
            for (int ct = 0; ct < 4; ++ct)
                acc[rt][ct] = __builtin_amdgcn_mfma_f32_16x16x32_bf16(
                    af[rt], bf[ct], acc[rt][ct], 0, 0, 0);
    }
    for (int ks = 0; ks < 16; ++ks) {
        const int k0 = ks * 32 + q * 8;
        bf16x8_t af = *(const bf16x8_t*)&h_lds[k0];
        bf16x8_t bf[4];
        #pragma unroll
        for (int ct = 0; ct < 4; ++ct)
            bf[ct] = *(const bf16x8_t*)&Whb[(size_t)(dBase + ct * 16) * CDIM + k0];
        #pragma unroll
        for (int rt = 0; rt < 4; ++rt)
            #pragma unroll
            for (int ct = 0; ct < 4; ++ct)
                acc[rt][ct] = __builtin_amdgcn_mfma_f32_16x16x32_bf16(
                    af, bf[ct], acc[rt][ct], 0, 0, 0);
    }
    float part[4][4];
    #pragma unroll
    for (int rt = 0; rt < 4; ++rt)
        #pragma unroll
        for (int rg = 0; rg < 4; ++rg) part[rt][rg] = 0.f;
    #pragma unroll
    for (int ct = 0; ct < 4; ++ct) {
        const int d = dBase + ct * 16;
        const float bias = babh_lds[d], wd = wd_lds[d];
        #pragma unroll
        for (int rt = 0; rt < 4; ++rt)
            #pragma unroll
            for (int rg = 0; rg < 4; ++rg) {
                float x = acc[rt][ct][rg] + bias;
                float e = __expf(2.f * x);
                part[rt][rg] += (1.f - 2.f / (e + 1.f)) * wd;
            }
    }
    #pragma unroll
    for (int m = 1; m < 16; m <<= 1)
        #pragma unroll
        for (int rt = 0; rt < 4; ++rt)
            #pragma unroll
            for (int rg = 0; rg < 4; ++rg)
                part[rt][rg] += __shfl_xor(part[rt][rg], m, 64);
    if (r == 0) {
        #pragma unroll
        for (int rt = 0; rt < 4; ++rt)
            #pragma unroll
            for (int rg = 0; rg < 4; ++rg)
                atomicAdd(&scores_lds[rt * 16 + q * 4 + rg], part[rt][rg]);
    }
    __syncthreads();
    if (wave == 0) {
        float v = (lane < NPOS) ? scores_lds[lane] : -3.0e38f;
        float vmax = v;
        #pragma unroll
        for (int m = 1; m < 64; m <<= 1) vmax = fmaxf(vmax, __shfl_xor(vmax, m, 64));
        float e = (lane < NPOS) ? __expf(v - vmax) : 0.f;
        float s = e;
        #pragma unroll
        for (int m = 1; m < 64; m <<= 1) s += __shfl_xor(s, m, 64);
        if (lane < NPOS) weights_lds[lane] = e / s;
    }
    __syncthreads();
    float sum = 0.f;
    #pragma unroll
    for (int n = 0; n < NPOS; ++n)
        sum += __bfloat162float(a_lds[n * ASTRIDE + t]) * weights_lds[n];
    out[b * CDIM + t] = sum;
}

// ===========================================================================
extern "C" void kernel_launch(void* const* d_in, const int* in_sizes, int n_in,
                              void* d_out, int out_size, void* d_ws, size_t ws_size,
                              hipStream_t stream) {
    const float* att_v = (const float*)d_in[0];
    const float* h     = (const float*)d_in[1];
    const float* Wa    = (const float*)d_in[2];
    const float* ba    = (const float*)d_in[3];
    const float* Wh    = (const float*)d_in[4];
    const float* bh    = (const float*)d_in[5];
    const float* Wd    = (const float*)d_in[6];
    // d_in[7] = bd: dropped (softmax shift-invariant)

    if (ws_size >= WS_NEED) {
        char* ws = (char*)d_ws;
        __hip_bfloat16* Wab     = (__hip_bfloat16*)(ws);
        __hip_bfloat16* pooled  = (__hip_bfloat16*)(ws + 524288);
        float*          ahb     = (float*)(ws + 13369344);
        float*          scores  = (float*)(ws + 13893632);
        int*            counters= (int*)(ws + 13959168);

        k1_pool_prep_ah<<<4401, 256, 0, stream>>>(att_v, h, Wa, Wh, ba, bh,
                                                  pooled, Wab, ahb,
                                                  scores, counters);
        gemm_score_fused2<<<1024, 256, 0, stream>>>(pooled, Wab, ahb, Wd,
                                                    scores, counters,
                                                    (float*)d_out);
    } else {
        __hip_bfloat16* Wab = (__hip_bfloat16*)d_ws;
        __hip_bfloat16* Whb = Wab + (size_t)CDIM * CDIM;
        prep_convert<<<512, 256, 0, stream>>>(Wa, Wh, Wab, Whb);
        att_spp_main<<<BATCH, 512, 0, stream>>>(att_v, h, ba, bh, Wd, Wab, Whb,
                                                (float*)d_out);
    }
}